// Round 2
// baseline (928.323 us; speedup 1.0000x reference)
//
#include <hip/hip_runtime.h>
#include <hip/hip_bf16.h>
#include <math.h>
#include <stddef.h>

#define EPS 1e-5f

// dims (fixed by the problem)
#define F_IN 128
#define FE 32
#define H1D 16
#define HPD 16
#define NC 8

// params region layout (float offsets)
#define P_M1 0
#define P_M2 256
#define P_C1 512
#define P_C2 528
#define P_CU 544
#define P_CV 560
#define P_WF 576
#define P_BO 704

// ---------------- degree ----------------
__global__ __launch_bounds__(256) void k_deg(const int* __restrict__ src, const int* __restrict__ dst,
                                             float* __restrict__ dout, float* __restrict__ din, int E) {
    int e = blockIdx.x * blockDim.x + threadIdx.x;
    if (e < E) {
        atomicAdd(&dout[src[e]], 1.0f);
        atomicAdd(&din[dst[e]], 1.0f);
    }
}

// ---------------- s1 = (n_feats @ W1) * dinv_out ----------------
__global__ __launch_bounds__(256) void k_s1(const float* __restrict__ x, const float* __restrict__ W1,
                                            const float* __restrict__ dout, float* __restrict__ s1, int N) {
    __shared__ float w[F_IN * H1D];
    for (int i = threadIdx.x; i < F_IN * H1D; i += blockDim.x) w[i] = W1[i];
    __syncthreads();
    int t = blockIdx.x * blockDim.x + threadIdx.x;
    int n = t >> 4, j = t & 15;
    if (n >= N) return;
    const float* row = x + (size_t)n * F_IN;
    float acc = 0.f;
    #pragma unroll 8
    for (int k = 0; k < F_IN; ++k) acc += row[k] * w[k * H1D + j];
    s1[(size_t)n * H1D + j] = acc * rsqrtf(fmaxf(dout[n], 1.0f));
}

// ---------------- scatter 16ch: agg[dst] += s[src] ----------------
__global__ __launch_bounds__(256) void k_scatter1(const int* __restrict__ src, const int* __restrict__ dst,
                                                  const float* __restrict__ s, float* __restrict__ agg, int E) {
    int t = blockIdx.x * blockDim.x + threadIdx.x;
    if (t < E * 16) {
        int e = t >> 4, j = t & 15;
        atomicAdd(&agg[dst[e] * 16 + j], s[src[e] * 16 + j]);
    }
}

// ---------------- h1 = relu(agg1*dinv_in + b1), accumulate BN1 stats ----------------
__global__ __launch_bounds__(256) void k_h1(const float* __restrict__ agg1, const float* __restrict__ din,
                                            const float* __restrict__ b1, float* __restrict__ h1,
                                            float* __restrict__ stats, int N) {
    __shared__ float ssum[16], ssq[16];
    if (threadIdx.x < 16) { ssum[threadIdx.x] = 0.f; ssq[threadIdx.x] = 0.f; }
    __syncthreads();
    int t = blockIdx.x * blockDim.x + threadIdx.x;
    int n = t >> 4, j = t & 15;
    float v = 0.f;
    if (n < N) {
        v = fmaxf(agg1[(size_t)n * 16 + j] * rsqrtf(fmaxf(din[n], 1.f)) + b1[j], 0.f);
        h1[(size_t)n * 16 + j] = v;
    }
    atomicAdd(&ssum[j], v);
    atomicAdd(&ssq[j], v * v);
    __syncthreads();
    if (threadIdx.x < 16) {
        atomicAdd(&stats[threadIdx.x], ssum[threadIdx.x]);
        atomicAdd(&stats[16 + threadIdx.x], ssq[threadIdx.x]);
    }
}

// ---------------- fold BN1 + W2 + Wp1b/c into 16x16 M1,M2 + vectors ----------------
__global__ __launch_bounds__(256) void k_fold(const float* __restrict__ st, const float* __restrict__ g1,
                                              const float* __restrict__ be1, const float* __restrict__ W2,
                                              const float* __restrict__ b2, const float* __restrict__ Wp1,
                                              float* __restrict__ prm, int N) {
    __shared__ float scale[16], shift[16], d2[64];
    int t = threadIdx.x;
    if (t < 16) {
        float mu = st[t] / (float)N;
        float var = st[16 + t] / (float)N - mu * mu;
        float sc = g1[t] * rsqrtf(var + EPS);
        scale[t] = sc;
        shift[t] = be1[t] - mu * sc;
    }
    __syncthreads();
    if (t < 64) {
        float acc = 0.f;
        #pragma unroll
        for (int j = 0; j < 16; ++j) acc += shift[j] * W2[j * 64 + t];
        d2[t] = acc;
    }
    __syncthreads();
    {
        int j1 = t >> 4, j2 = t & 15;
        float m1 = 0.f, m2 = 0.f;
        float sc = scale[j1];
        for (int c = 0; c < 64; ++c) {
            float w = sc * W2[j1 * 64 + c];
            m1 += w * Wp1[(32 + c) * 16 + j2];
            m2 += w * Wp1[(96 + c) * 16 + j2];
        }
        prm[P_M1 + j1 * 16 + j2] = m1;
        prm[P_M2 + j1 * 16 + j2] = m2;
    }
    if (t < 16) {
        float a = 0.f, b = 0.f, u = 0.f, v = 0.f;
        for (int c = 0; c < 64; ++c) {
            float wb = Wp1[(32 + c) * 16 + t], wc = Wp1[(96 + c) * 16 + t];
            a += d2[c] * wb; b += d2[c] * wc;
            u += b2[c] * wb; v += b2[c] * wc;
        }
        prm[P_C1 + t] = a; prm[P_C2 + t] = b;
        prm[P_CU + t] = u; prm[P_CV + t] = v;
    }
}

// ---------------- t1/t2 = dinv_out * (h1 @ M + c) ----------------
__global__ __launch_bounds__(256) void k_t(const float* __restrict__ h1, const float* __restrict__ dout,
                                           const float* __restrict__ prm, float* __restrict__ t1,
                                           float* __restrict__ t2, int N) {
    __shared__ float M1[256], M2[256], c1[16], c2[16];
    for (int i = threadIdx.x; i < 256; i += blockDim.x) { M1[i] = prm[P_M1 + i]; M2[i] = prm[P_M2 + i]; }
    if (threadIdx.x < 16) { c1[threadIdx.x] = prm[P_C1 + threadIdx.x]; c2[threadIdx.x] = prm[P_C2 + threadIdx.x]; }
    __syncthreads();
    int t = blockIdx.x * blockDim.x + threadIdx.x;
    int n = t >> 4, j = t & 15;
    if (n >= N) return;
    float div = rsqrtf(fmaxf(dout[n], 1.f));
    const float* h = h1 + (size_t)n * 16;
    float a = c1[j], b = c2[j];
    #pragma unroll
    for (int k = 0; k < 16; ++k) { float x = h[k]; a += x * M1[k * 16 + j]; b += x * M2[k * 16 + j]; }
    t1[(size_t)n * 16 + j] = a * div;
    t2[(size_t)n * 16 + j] = b * div;
}

// ---------------- scatter two 16ch tables ----------------
__global__ __launch_bounds__(256) void k_scatter2(const int* __restrict__ src, const int* __restrict__ dst,
                                                  const float* __restrict__ t1, const float* __restrict__ t2,
                                                  float* __restrict__ aggT, float* __restrict__ aggT2, int E) {
    int t = blockIdx.x * blockDim.x + threadIdx.x;
    if (t < E * 16) {
        int e = t >> 4, j = t & 15;
        int si = src[e] * 16 + j, di = dst[e] * 16 + j;
        atomicAdd(&aggT[di], t1[si]);
        atomicAdd(&aggT2[di], t2[si]);
    }
}

// ---------------- U,V finalize (in-place on aggT/aggT2) ----------------
__global__ __launch_bounds__(256) void k_uv(float* __restrict__ U, float* __restrict__ V,
                                            const float* __restrict__ din, const float* __restrict__ prm, int N) {
    int t = blockIdx.x * blockDim.x + threadIdx.x;
    int n = t >> 4, j = t & 15;
    if (n >= N) return;
    float div = rsqrtf(fmaxf(din[n], 1.f));
    U[(size_t)n * 16 + j] = U[(size_t)n * 16 + j] * div + prm[P_CU + j];
    V[(size_t)n * 16 + j] = V[(size_t)n * 16 + j] * div + prm[P_CV + j];
}

// ---------------- shared per-edge z computation ----------------
__device__ __forceinline__ void compute_z(int e, const float* __restrict__ ef,
                                          const int* __restrict__ src, const int* __restrict__ dst,
                                          const float* wa, const float* bb,
                                          const float* __restrict__ U, const float* __restrict__ V,
                                          float* z) {
    int s = src[e], d = dst[e];
    const float4* up = (const float4*)(U + (size_t)s * 16);
    const float4* vp = (const float4*)(V + (size_t)d * 16);
    #pragma unroll
    for (int q = 0; q < 4; ++q) {
        float4 uu = up[q], vv = vp[q];
        z[q * 4 + 0] = bb[q * 4 + 0] + uu.x + vv.x;
        z[q * 4 + 1] = bb[q * 4 + 1] + uu.y + vv.y;
        z[q * 4 + 2] = bb[q * 4 + 2] + uu.z + vv.z;
        z[q * 4 + 3] = bb[q * 4 + 3] + uu.w + vv.w;
    }
    const float4* ep = (const float4*)(ef + (size_t)e * FE);
    #pragma unroll
    for (int q = 0; q < 8; ++q) {
        float4 x4 = ep[q];
        float xs[4] = {x4.x, x4.y, x4.z, x4.w};
        #pragma unroll
        for (int kk = 0; kk < 4; ++kk) {
            float x = xs[kk];
            #pragma unroll
            for (int j = 0; j < 16; ++j) z[j] += x * wa[(q * 4 + kk) * 16 + j];
        }
    }
}

// ---------------- edge pass 1: z0 + BN2 stats ----------------
__global__ __launch_bounds__(256) void k_edge1(const float* __restrict__ ef, const int* __restrict__ src,
                                               const int* __restrict__ dst, const float* __restrict__ Wp1,
                                               const float* __restrict__ bp1, const float* __restrict__ U,
                                               const float* __restrict__ V, float* __restrict__ z0,
                                               float* __restrict__ statsp, int E) {
    __shared__ float wa[FE * HPD];
    __shared__ float bb[HPD];
    __shared__ float red[2 * HPD];
    for (int i = threadIdx.x; i < FE * HPD; i += blockDim.x) wa[i] = Wp1[i];
    if (threadIdx.x < HPD) { bb[threadIdx.x] = bp1[threadIdx.x]; red[threadIdx.x] = 0.f; red[HPD + threadIdx.x] = 0.f; }
    __syncthreads();
    float sum[16], sq[16];
    #pragma unroll
    for (int j = 0; j < 16; ++j) { sum[j] = 0.f; sq[j] = 0.f; }
    int stride = gridDim.x * blockDim.x;
    for (int e = blockIdx.x * blockDim.x + threadIdx.x; e < E; e += stride) {
        float z[16];
        compute_z(e, ef, src, dst, wa, bb, U, V, z);
        if (z0) {
            float4* zp = (float4*)(z0 + (size_t)e * 16);
            zp[0] = make_float4(z[0], z[1], z[2], z[3]);
            zp[1] = make_float4(z[4], z[5], z[6], z[7]);
            zp[2] = make_float4(z[8], z[9], z[10], z[11]);
            zp[3] = make_float4(z[12], z[13], z[14], z[15]);
        }
        #pragma unroll
        for (int j = 0; j < 16; ++j) { sum[j] += z[j]; sq[j] += z[j] * z[j]; }
    }
    // wave reduction (64 lanes)
    #pragma unroll
    for (int j = 0; j < 16; ++j) {
        #pragma unroll
        for (int m = 1; m < 64; m <<= 1) {
            sum[j] += __shfl_xor(sum[j], m, 64);
            sq[j]  += __shfl_xor(sq[j], m, 64);
        }
    }
    if ((threadIdx.x & 63) == 0) {
        #pragma unroll
        for (int j = 0; j < 16; ++j) { atomicAdd(&red[j], sum[j]); atomicAdd(&red[HPD + j], sq[j]); }
    }
    __syncthreads();
    if (threadIdx.x < HPD) {
        atomicAdd(&statsp[threadIdx.x], red[threadIdx.x]);
        atomicAdd(&statsp[HPD + threadIdx.x], red[HPD + threadIdx.x]);
    }
}

// ---------------- fold BN2 into Wp2 ----------------
__global__ __launch_bounds__(128) void k_fold2(const float* __restrict__ stp, const float* __restrict__ gp,
                                               const float* __restrict__ bep, const float* __restrict__ Wp2,
                                               const float* __restrict__ bp2, float* __restrict__ prm, int E) {
    __shared__ float sc[16], sh[16];
    int t = threadIdx.x;
    if (t < 16) {
        float mu = stp[t] / (float)E;
        float var = stp[16 + t] / (float)E - mu * mu;
        float s = gp[t] * rsqrtf(var + EPS);
        sc[t] = s;
        sh[t] = bep[t] - mu * s;
    }
    __syncthreads();
    if (t < 128) { int j = t >> 3, k = t & 7; prm[P_WF + t] = sc[j] * Wp2[j * 8 + k]; }
    if (t < 8) {
        float a = bp2[t];
        #pragma unroll
        for (int j = 0; j < 16; ++j) a += sh[j] * Wp2[j * 8 + t];
        prm[P_BO + t] = a;
    }
}

// ---------------- logits + log_softmax writer ----------------
__device__ __forceinline__ void logits_out(int e, const float* z, const float* wf, const float* bo,
                                           float* __restrict__ out) {
    float l[8];
    #pragma unroll
    for (int k = 0; k < 8; ++k) l[k] = bo[k];
    #pragma unroll
    for (int j = 0; j < 16; ++j) {
        float x = z[j];
        #pragma unroll
        for (int k = 0; k < 8; ++k) l[k] += x * wf[j * 8 + k];
    }
    float m = l[0];
    #pragma unroll
    for (int k = 1; k < 8; ++k) m = fmaxf(m, l[k]);
    float s = 0.f;
    #pragma unroll
    for (int k = 0; k < 8; ++k) s += expf(l[k] - m);
    float r = m + logf(s);
    float4* op = (float4*)(out + (size_t)e * 8);
    op[0] = make_float4(l[0] - r, l[1] - r, l[2] - r, l[3] - r);
    op[1] = make_float4(l[4] - r, l[5] - r, l[6] - r, l[7] - r);
}

// ---------------- edge pass 2 (read stored z0) ----------------
__global__ __launch_bounds__(256) void k_edge2(const float* __restrict__ z0, const float* __restrict__ prm,
                                               float* __restrict__ out, int E) {
    __shared__ float wf[128], bo[8];
    if (threadIdx.x < 128) wf[threadIdx.x] = prm[P_WF + threadIdx.x];
    if (threadIdx.x < 8) bo[threadIdx.x] = prm[P_BO + threadIdx.x];
    __syncthreads();
    int e = blockIdx.x * blockDim.x + threadIdx.x;
    if (e >= E) return;
    float z[16];
    const float4* zp = (const float4*)(z0 + (size_t)e * 16);
    float4 a0 = zp[0], a1 = zp[1], a2 = zp[2], a3 = zp[3];
    z[0]=a0.x; z[1]=a0.y; z[2]=a0.z; z[3]=a0.w;
    z[4]=a1.x; z[5]=a1.y; z[6]=a1.z; z[7]=a1.w;
    z[8]=a2.x; z[9]=a2.y; z[10]=a2.z; z[11]=a2.w;
    z[12]=a3.x; z[13]=a3.y; z[14]=a3.z; z[15]=a3.w;
    logits_out(e, z, wf, bo, out);
}

// ---------------- edge pass 2 (recompute z, fallback if ws too small) ----------------
__global__ __launch_bounds__(256) void k_edge2_rc(const float* __restrict__ ef, const int* __restrict__ src,
                                                  const int* __restrict__ dst, const float* __restrict__ Wp1,
                                                  const float* __restrict__ bp1, const float* __restrict__ U,
                                                  const float* __restrict__ V, const float* __restrict__ prm,
                                                  float* __restrict__ out, int E) {
    __shared__ float wa[FE * HPD];
    __shared__ float bb[HPD];
    __shared__ float wf[128], bo[8];
    for (int i = threadIdx.x; i < FE * HPD; i += blockDim.x) wa[i] = Wp1[i];
    if (threadIdx.x < HPD) bb[threadIdx.x] = bp1[threadIdx.x];
    if (threadIdx.x < 128) wf[threadIdx.x] = prm[P_WF + threadIdx.x];
    if (threadIdx.x < 8) bo[threadIdx.x] = prm[P_BO + threadIdx.x];
    __syncthreads();
    int e = blockIdx.x * blockDim.x + threadIdx.x;
    if (e >= E) return;
    float z[16];
    compute_z(e, ef, src, dst, wa, bb, U, V, z);
    logits_out(e, z, wf, bo, out);
}

extern "C" void kernel_launch(void* const* d_in, const int* in_sizes, int n_in,
                              void* d_out, int out_size, void* d_ws, size_t ws_size,
                              hipStream_t stream) {
    const float* n_feats = (const float*)d_in[0];
    const float* e_feats = (const float*)d_in[1];
    const int*   src     = (const int*)d_in[2];
    const int*   dst     = (const int*)d_in[3];
    const float* W1      = (const float*)d_in[4];
    const float* b1      = (const float*)d_in[5];
    const float* g1      = (const float*)d_in[6];
    const float* be1     = (const float*)d_in[7];
    const float* W2      = (const float*)d_in[8];
    const float* b2      = (const float*)d_in[9];
    const float* Wp1     = (const float*)d_in[10];
    const float* bp1     = (const float*)d_in[11];
    const float* gp      = (const float*)d_in[12];
    const float* bep     = (const float*)d_in[13];
    const float* Wp2     = (const float*)d_in[14];
    const float* bp2     = (const float*)d_in[15];
    float* out = (float*)d_out;

    int N = in_sizes[0] / F_IN;
    int E = in_sizes[2];
    float* ws = (float*)d_ws;

    // workspace layout (floats); zero-required regions first
    size_t off = 0;
    auto take = [&](size_t n) { size_t r = off; off += (n + 15) & ~(size_t)15; return r; };
    size_t o_dout  = take((size_t)N);
    size_t o_din   = take((size_t)N);
    size_t o_agg1  = take((size_t)16 * N);
    size_t o_aggT  = take((size_t)16 * N);
    size_t o_aggT2 = take((size_t)16 * N);
    size_t o_st1   = take(32);
    size_t o_stp   = take(32);
    size_t o_prm   = take(1024);
    size_t zeroFloats = off;
    size_t o_s1 = take((size_t)16 * N);
    size_t o_h1 = take((size_t)16 * N);
    size_t o_t1 = take((size_t)16 * N);
    size_t o_t2 = take((size_t)16 * N);
    size_t o_z0 = off;
    bool store_z = ws_size >= (off + (size_t)16 * E) * sizeof(float);

    hipMemsetAsync(ws, 0, zeroFloats * sizeof(float), stream);

    int bE = (E + 255) / 256;
    int bN16 = (N * 16 + 255) / 256;
    int bE16 = (int)(((size_t)E * 16 + 255) / 256);

    k_deg<<<bE, 256, 0, stream>>>(src, dst, ws + o_dout, ws + o_din, E);
    k_s1<<<bN16, 256, 0, stream>>>(n_feats, W1, ws + o_dout, ws + o_s1, N);
    k_scatter1<<<bE16, 256, 0, stream>>>(src, dst, ws + o_s1, ws + o_agg1, E);
    k_h1<<<bN16, 256, 0, stream>>>(ws + o_agg1, ws + o_din, b1, ws + o_h1, ws + o_st1, N);
    k_fold<<<1, 256, 0, stream>>>(ws + o_st1, g1, be1, W2, b2, Wp1, ws + o_prm, N);
    k_t<<<bN16, 256, 0, stream>>>(ws + o_h1, ws + o_dout, ws + o_prm, ws + o_t1, ws + o_t2, N);
    k_scatter2<<<bE16, 256, 0, stream>>>(src, dst, ws + o_t1, ws + o_t2, ws + o_aggT, ws + o_aggT2, E);
    k_uv<<<bN16, 256, 0, stream>>>(ws + o_aggT, ws + o_aggT2, ws + o_din, ws + o_prm, N);

    int bEdge1 = (E + 256 * 8 - 1) / (256 * 8);
    k_edge1<<<bEdge1, 256, 0, stream>>>(e_feats, src, dst, Wp1, bp1, ws + o_aggT, ws + o_aggT2,
                                        store_z ? ws + o_z0 : (float*)nullptr, ws + o_stp, E);
    k_fold2<<<1, 128, 0, stream>>>(ws + o_stp, gp, bep, Wp2, bp2, ws + o_prm, E);
    if (store_z) {
        k_edge2<<<bE, 256, 0, stream>>>(ws + o_z0, ws + o_prm, out, E);
    } else {
        k_edge2_rc<<<bE, 256, 0, stream>>>(e_feats, src, dst, Wp1, bp1, ws + o_aggT, ws + o_aggT2,
                                           ws + o_prm, out, E);
    }
}